// Round 6
// baseline (36674.692 us; speedup 1.0000x reference)
//
#include <hip/hip_runtime.h>
#include <hip/hip_bf16.h>

// Problem constants (fixed shapes per reference setup_inputs; n_step = 200).
#define MM 64
#define NN 4096
#define KK 4096
#define NSTEP 200

typedef __bf16 bf16x8 __attribute__((ext_vector_type(8)));
typedef float  f32x4  __attribute__((ext_vector_type(4)));

static __device__ __forceinline__ unsigned short f2bf(float f) {
    __hip_bfloat16 h = __float2bfloat16(f);
    return __builtin_bit_cast(unsigned short, h);
}
static __device__ __forceinline__ float bf2f(unsigned short u) {
    __hip_bfloat16 h = __builtin_bit_cast(__hip_bfloat16, u);
    return __bfloat162float(h);
}

// Fragment layouts (mfma_f32_16x16x32_bf16, m89 mapping:
//   frag[lane=q*16+l16][j] = Mat[row16=l16][k=q*8+j]):
// A (g):  addr(m,kg) = ((kc*4 + (m>>4))*64 + q*16 + (m&15))*8 + j
// B (W):  addr(n,kg) = (((n>>4)*128 + kc)*64 + q*16 + (n&15))*8 + j

// ---------------------------------------------------------------------------
// Prologue 1: s = 0.5*(W[n][k]+W[k][n]), diag zero; (hi,lo) bf16 split,
// scattered into B-fragment order. 64x64 tiles, LDS transpose.
// ---------------------------------------------------------------------------
__global__ __launch_bounds__(256) void symm_kernel(const float* __restrict__ W,
                                                   unsigned short* __restrict__ Wfh,
                                                   unsigned short* __restrict__ Wfl) {
    __shared__ float T[64][65];
    const int tid = threadIdx.x;
    const int r0 = blockIdx.y * 64, c0 = blockIdx.x * 64;
#pragma unroll
    for (int i = 0; i < 4; ++i) {
        int lin = tid + i * 256;
        int cc  = lin >> 4;
        int r4  = (lin & 15) * 4;
        float4 v = *(const float4*)&W[(size_t)(c0 + cc) * NN + r0 + r4];
        T[cc][r4 + 0] = v.x; T[cc][r4 + 1] = v.y;
        T[cc][r4 + 2] = v.z; T[cc][r4 + 3] = v.w;
    }
    __syncthreads();
#pragma unroll
    for (int i = 0; i < 4; ++i) {
        int lin = tid + i * 256;
        int rr  = lin >> 4;
        int c4  = (lin & 15) * 4;
        float4 v = *(const float4*)&W[(size_t)(r0 + rr) * NN + c0 + c4];
        float d[4] = {v.x, v.y, v.z, v.w};
        ushort4 ohi, olo;
        unsigned short* ph = (unsigned short*)&ohi;
        unsigned short* pl = (unsigned short*)&olo;
#pragma unroll
        for (int j = 0; j < 4; ++j) {
            float sv = 0.5f * (d[j] + T[c4 + j][rr]);
            if (r0 + rr == c0 + c4 + j) sv = 0.0f;
            unsigned short hi = f2bf(sv);
            ph[j] = hi;
            pl[j] = f2bf(sv - bf2f(hi));
        }
        const int n  = r0 + rr;            // W row == output column
        const int kg = c0 + c4;            // 4-aligned
        const int s16 = n >> 4, ln = n & 15;
        const int kc = kg >> 5, q = (kg & 31) >> 3, j0 = kg & 7;
        size_t off = (((size_t)s16 * 128 + kc) * 64 + q * 16 + ln) * 8 + j0;
        *(ushort4*)&Wfh[off] = ohi;        // 8B-aligned
        *(ushort4*)&Wfl[off] = olo;
    }
}

// ---------------------------------------------------------------------------
// Prologue 2: x0 = (1/beta)*log(g/(1-g)) (plain layout); g -> A-frag (hi,lo)
// ---------------------------------------------------------------------------
__global__ __launch_bounds__(256) void init_kernel(const float* __restrict__ g_in,
                                                   const float* __restrict__ beta,
                                                   float* __restrict__ x,
                                                   unsigned short* __restrict__ gfh,
                                                   unsigned short* __restrict__ gfl) {
    int idx = blockIdx.x * 256 + threadIdx.x;
    int r = idx >> 12, c = idx & (NN - 1);
    float g = g_in[idx];
    x[idx] = logf(g / (1.0f - g)) / beta[c];
    unsigned short hi = f2bf(g);
    unsigned short lo = f2bf(g - bf2f(hi));
    size_t off = (((size_t)(c >> 5) * 4 + (r >> 4)) * 64 + ((c & 31) >> 3) * 16 + (r & 15)) * 8 + (c & 7);
    gfh[off] = hi;
    gfl[off] = lo;
}

// ---------------------------------------------------------------------------
// Prologue 3: max_x = 50 / max(beta); also zero the per-strip arrival counters
// (re-zeroed every kernel_launch so hipGraph replays are safe).
// ---------------------------------------------------------------------------
__global__ __launch_bounds__(256) void maxx_kernel(const float* __restrict__ beta,
                                                   float* __restrict__ out,
                                                   unsigned* __restrict__ cnt) {
    __shared__ float red[256];
    float m = -1e30f;
    for (int i = threadIdx.x; i < NN; i += 256) m = fmaxf(m, beta[i]);
    red[threadIdx.x] = m;
    if (threadIdx.x < 64) cnt[threadIdx.x] = 0u;
    __syncthreads();
    for (int s = 128; s > 0; s >>= 1) {
        if (threadIdx.x < s) red[threadIdx.x] = fmaxf(red[threadIdx.x], red[threadIdx.x + s]);
        __syncthreads();
    }
    if (threadIdx.x == 0) out[0] = 50.0f / red[0];
}

// ---------------------------------------------------------------------------
// Fused step kernel v3: split-K + last-arriver fixup, ONE dispatch per step.
// v2 (17.9 us/step) was L2-bound: 256 col-strips each re-read the FULL g
// stream -> 256 MB/step via L2. g-traffic = (#strips) x 1MB independent of
// K-split depth, so v3 uses 64 strips of 64 cols x 4 K-quarters (still 256
// blocks = 1/CU): g-traffic drops 4x to 64 MB/step; W unchanged.
// Cross-block K-reduction: each block writes a 16 KB fp32 partial to P,
// release-fence + device atomicAdd on cnt[strip]; the LAST arriver (old ==
// 4*st+3; counters monotonic across steps) acquires and runs the epilogue.
// No spinning, no grid sync. XCD note: kq=bx&3, XCD=bx%8 -> each XCD sees
// exactly one g k-slice (256 KB, L2-resident).
// ---------------------------------------------------------------------------
__global__ __launch_bounds__(1024, 1) void step_kernel(
    const unsigned short* __restrict__ gfh,
    const unsigned short* __restrict__ gfl,
    const unsigned short* __restrict__ Wfh,
    const unsigned short* __restrict__ Wfl,
    float* __restrict__ x,
    unsigned short* __restrict__ gfh_out,
    unsigned short* __restrict__ gfl_out,
    const float* __restrict__ bvec,
    const float* __restrict__ beta,
    const float* __restrict__ tau,
    const float* __restrict__ dt_ptr,
    const float* __restrict__ maxx_ptr,
    float* __restrict__ P,                    // [4][64][64][64] fp32 partials
    unsigned* __restrict__ cnt,               // [64] per-strip arrival counters
    int st,                                   // step index (counter target)
    float* __restrict__ gout_f32)             // non-null on last step only
{
    __shared__ float sacc[16][16][65];        // [wave][mq*4+rg][lane], +1 pad
    __shared__ unsigned sOld;

    const int tid  = threadIdx.x;
    const int w    = tid >> 6;
    const int lane = tid & 63;
    const int s64  = blockIdx.x >> 2;         // 64-col strip 0..63
    const int kq   = blockIdx.x & 3;          // K-quarter 0..3 (1024 k)
    const int nq   = w & 3;                   // wave's 16-col group in strip
    const int kq4  = w >> 2;                  // wave's 256-k sub-slice

    f32x4 acc[4] = {};                        // 4 m-subtiles x (16x16) frag

#pragma unroll
    for (int it = 0; it < 8; ++it) {
        const int kc = kq * 32 + kq4 * 8 + it;       // 32-wide K chunk
        const size_t aBase = (size_t)kc * 2048 + lane * 8;          // + mq*512
        const int n16 = s64 * 4 + nq;
        const size_t bOff = (((size_t)n16 * 128 + kc) * 64 + lane) * 8;
        bf16x8 bh = *(const bf16x8*)&Wfh[bOff];
        bf16x8 bl = *(const bf16x8*)&Wfl[bOff];
        bf16x8 ah[4], al[4];
#pragma unroll
        for (int mq = 0; mq < 4; ++mq) {
            ah[mq] = *(const bf16x8*)&gfh[aBase + (size_t)mq * 512];
            al[mq] = *(const bf16x8*)&gfl[aBase + (size_t)mq * 512];
        }
#pragma unroll
        for (int mq = 0; mq < 4; ++mq) {
            acc[mq] = __builtin_amdgcn_mfma_f32_16x16x32_bf16(ah[mq], bh, acc[mq], 0, 0, 0);
            acc[mq] = __builtin_amdgcn_mfma_f32_16x16x32_bf16(al[mq], bh, acc[mq], 0, 0, 0);
            acc[mq] = __builtin_amdgcn_mfma_f32_16x16x32_bf16(ah[mq], bl, acc[mq], 0, 0, 0);
        }
    }

    // Dump wave partials to LDS.
#pragma unroll
    for (int mq = 0; mq < 4; ++mq)
#pragma unroll
        for (int rg = 0; rg < 4; ++rg)
            sacc[w][mq * 4 + rg][lane] = acc[mq][rg];
    __syncthreads();

    // Intra-block 4-way kq4 reduction -> P[kq][s64][64 rows][64 cols].
    // Thread t: row m = t>>4, cols c = (t&15)*4 .. +3 (float4 store).
    {
        const int m  = tid >> 4;
        const int tt = tid & 15;
        const int mq = m >> 4, qq = (m & 15) >> 2, rg = m & 3;
        const int ridx = mq * 4 + rg;
        const int nq_c = tt >> 2;             // (c>>4) for c = tt*4+j
        float4 pv;
#pragma unroll
        for (int j = 0; j < 4; ++j) {
            const int cl = qq * 16 + (tt & 3) * 4 + j;
            (&pv.x)[j] = sacc[nq_c][ridx][cl] + sacc[4 + nq_c][ridx][cl]
                       + sacc[8 + nq_c][ridx][cl] + sacc[12 + nq_c][ridx][cl];
        }
        *(float4*)&P[(((size_t)(kq * 64 + s64) * 64 + m) * 64) + tt * 4] = pv;
    }

    // Release: make P stores visible device-wide, then signal arrival.
    __threadfence();
    __syncthreads();
    if (tid == 0) sOld = atomicAdd(&cnt[s64], 1u);
    __syncthreads();
    if (sOld != (unsigned)(4 * st + 3)) return;   // not the last arriver

    // Acquire: invalidate stale cache so remote P slices are seen.
    __threadfence();

    // Epilogue (last arriver only): 4096 outputs, 4 per thread.
    {
        const int m  = tid >> 4;
        const int tt = tid & 15;
        const int c0 = tt * 4;
        const int n0 = s64 * 64 + c0;         // global col, 4-aligned
        const size_t pb = ((size_t)s64 * 64 + m) * 64 + c0;
        float4 p0 = *(const float4*)&P[pb];
        float4 p1 = *(const float4*)&P[(size_t)(1 * 64) * 4096 + pb];
        float4 p2 = *(const float4*)&P[(size_t)(2 * 64) * 4096 + pb];
        float4 p3 = *(const float4*)&P[(size_t)(3 * 64) * 4096 + pb];
        float sum[4] = {p0.x + p1.x + p2.x + p3.x,
                        p0.y + p1.y + p2.y + p3.y,
                        p0.z + p1.z + p2.z + p3.z,
                        p0.w + p1.w + p2.w + p3.w};

        const float dt = *dt_ptr;
        const float mx = *maxx_ptr;
        float4 b0 = *(const float4*)&bvec[n0];
        float4 e0 = *(const float4*)&beta[n0];
        float4 t0 = *(const float4*)&tau[n0];
        float bb[4] = {b0.x, b0.y, b0.z, b0.w};
        float be[4] = {e0.x, e0.y, e0.z, e0.w};
        float tv[4] = {t0.x, t0.y, t0.z, t0.w};

        float* xp = &x[(size_t)m * NN + n0];
        float4 x0 = *(const float4*)xp;
        float xo[4] = {x0.x, x0.y, x0.z, x0.w};

        float gg[4];
        unsigned short vh[4], vl[4];
#pragma unroll
        for (int j = 0; j < 4; ++j) {
            const float al = dt / tv[j];
            float xn = al * (sum[j] + bb[j]) + (1.0f - al) * xo[j];
            xn = fminf(fmaxf(xn, -mx), mx);
            float g = 1.0f / (1.0f + __expf(-be[j] * xn));
            xo[j] = xn;
            gg[j] = g;
            unsigned short hi = f2bf(g);
            vh[j] = hi;
            vl[j] = f2bf(g - bf2f(hi));
        }
        *(float4*)xp = {xo[0], xo[1], xo[2], xo[3]};

        // A-fragment scatter for (m, kg = n0..n0+3); n0%8 in {0,4} -> ushort4.
        size_t off = (((size_t)(n0 >> 5) * 4 + (m >> 4)) * 64 + ((n0 & 31) >> 3) * 16 + (m & 15)) * 8 + (n0 & 7);
        *(ushort4*)&gfh_out[off] = {vh[0], vh[1], vh[2], vh[3]};
        *(ushort4*)&gfl_out[off] = {vl[0], vl[1], vl[2], vl[3]};

        if (gout_f32)
            *(float4*)&gout_f32[(size_t)m * NN + n0] = {gg[0], gg[1], gg[2], gg[3]};
    }
}

// ---------------------------------------------------------------------------
extern "C" void kernel_launch(void* const* d_in, const int* in_sizes, int n_in,
                              void* d_out, int out_size, void* d_ws, size_t ws_size,
                              hipStream_t stream) {
    const float* state_g = (const float*)d_in[0];
    const float* W       = (const float*)d_in[1];
    const float* b       = (const float*)d_in[2];
    const float* beta    = (const float*)d_in[3];
    const float* tau     = (const float*)d_in[4];
    const float* dt      = (const float*)d_in[5];
    float* out = (float*)d_out;

    char* ws = (char*)d_ws;
    const size_t WH = (size_t)KK * NN * 2;    // 32 MB per W-frag array
    const size_t XB = (size_t)MM * NN * 4;    // 1 MB
    const size_t GB = (size_t)MM * NN * 2;    // 512 KB per g-frag array
    const size_t PB = (size_t)4 * 64 * 64 * 64 * 4;   // 4 MB partials
    unsigned short* Wfh = (unsigned short*)ws;
    unsigned short* Wfl = (unsigned short*)(ws + WH);
    float*          x   = (float*)(ws + 2 * WH);
    unsigned short* g0h = (unsigned short*)(ws + 2 * WH + XB);
    unsigned short* g0l = (unsigned short*)(ws + 2 * WH + XB + GB);
    unsigned short* g1h = (unsigned short*)(ws + 2 * WH + XB + 2 * GB);
    unsigned short* g1l = (unsigned short*)(ws + 2 * WH + XB + 3 * GB);
    float*          P   = (float*)(ws + 2 * WH + XB + 4 * GB);
    unsigned*       cnt = (unsigned*)(ws + 2 * WH + XB + 4 * GB + PB);
    float*          mxp = (float*)(ws + 2 * WH + XB + 4 * GB + PB + 256);

    symm_kernel<<<dim3(64, 64), 256, 0, stream>>>(W, Wfh, Wfl);
    init_kernel<<<(MM * NN) / 256, 256, 0, stream>>>(state_g, beta, x, g0h, g0l);
    maxx_kernel<<<1, 256, 0, stream>>>(beta, mxp, cnt);

    unsigned short *gih = g0h, *gil = g0l, *goh = g1h, *gol = g1l;
    for (int st = 0; st < NSTEP; ++st) {
        float* of = (st == NSTEP - 1) ? out : nullptr;
        step_kernel<<<256, 1024, 0, stream>>>(gih, gil, Wfh, Wfl, x,
                                              goh, gol, b, beta, tau, dt, mxp,
                                              P, cnt, st, of);
        unsigned short* tp;
        tp = gih; gih = goh; goh = tp;
        tp = gil; gil = gol; gol = tp;
    }
}

// Round 7
// 3617.851 us; speedup vs baseline: 10.1371x; 10.1371x over previous
//
#include <hip/hip_runtime.h>
#include <hip/hip_bf16.h>

// Problem constants (fixed shapes per reference setup_inputs; n_step = 200).
#define MM 64
#define NN 4096
#define KK 4096
#define NSTEP 200

typedef __bf16 bf16x8 __attribute__((ext_vector_type(8)));
typedef float  f32x4  __attribute__((ext_vector_type(4)));

static __device__ __forceinline__ unsigned short f2bf(float f) {
    __hip_bfloat16 h = __float2bfloat16(f);
    return __builtin_bit_cast(unsigned short, h);
}
static __device__ __forceinline__ float bf2f(unsigned short u) {
    __hip_bfloat16 h = __builtin_bit_cast(__hip_bfloat16, u);
    return __bfloat162float(h);
}

// Fragment layouts (mfma_f32_16x16x32_bf16, m89 mapping:
//   frag[lane=q*16+l16][j] = Mat[row16=l16][k=q*8+j]):
// A (g):  addr(m,kg) = ((kc*4 + (m>>4))*64 + q*16 + (m&15))*8 + j
// B (W):  addr(n,kg) = (((n>>4)*128 + kc)*64 + q*16 + (n&15))*8 + j

// ---------------------------------------------------------------------------
// Prologue 1: s = 0.5*(W[n][k]+W[k][n]), diag zero; (hi,lo) bf16 split,
// scattered into B-fragment order. 64x64 tiles, LDS transpose.
// ---------------------------------------------------------------------------
__global__ __launch_bounds__(256) void symm_kernel(const float* __restrict__ W,
                                                   unsigned short* __restrict__ Wfh,
                                                   unsigned short* __restrict__ Wfl) {
    __shared__ float T[64][65];
    const int tid = threadIdx.x;
    const int r0 = blockIdx.y * 64, c0 = blockIdx.x * 64;
#pragma unroll
    for (int i = 0; i < 4; ++i) {
        int lin = tid + i * 256;
        int cc  = lin >> 4;
        int r4  = (lin & 15) * 4;
        float4 v = *(const float4*)&W[(size_t)(c0 + cc) * NN + r0 + r4];
        T[cc][r4 + 0] = v.x; T[cc][r4 + 1] = v.y;
        T[cc][r4 + 2] = v.z; T[cc][r4 + 3] = v.w;
    }
    __syncthreads();
#pragma unroll
    for (int i = 0; i < 4; ++i) {
        int lin = tid + i * 256;
        int rr  = lin >> 4;
        int c4  = (lin & 15) * 4;
        float4 v = *(const float4*)&W[(size_t)(r0 + rr) * NN + c0 + c4];
        float d[4] = {v.x, v.y, v.z, v.w};
        ushort4 ohi, olo;
        unsigned short* ph = (unsigned short*)&ohi;
        unsigned short* pl = (unsigned short*)&olo;
#pragma unroll
        for (int j = 0; j < 4; ++j) {
            float sv = 0.5f * (d[j] + T[c4 + j][rr]);
            if (r0 + rr == c0 + c4 + j) sv = 0.0f;
            unsigned short hi = f2bf(sv);
            ph[j] = hi;
            pl[j] = f2bf(sv - bf2f(hi));
        }
        const int n  = r0 + rr;            // W row == output column
        const int kg = c0 + c4;            // 4-aligned
        const int s16 = n >> 4, ln = n & 15;
        const int kc = kg >> 5, q = (kg & 31) >> 3, j0 = kg & 7;
        size_t off = (((size_t)s16 * 128 + kc) * 64 + q * 16 + ln) * 8 + j0;
        *(ushort4*)&Wfh[off] = ohi;        // 8B-aligned
        *(ushort4*)&Wfl[off] = olo;
    }
}

// ---------------------------------------------------------------------------
// Prologue 2: x0 = (1/beta)*log(g/(1-g)) (plain layout); g -> A-frag (hi,lo)
// ---------------------------------------------------------------------------
__global__ __launch_bounds__(256) void init_kernel(const float* __restrict__ g_in,
                                                   const float* __restrict__ beta,
                                                   float* __restrict__ x,
                                                   unsigned short* __restrict__ gfh,
                                                   unsigned short* __restrict__ gfl) {
    int idx = blockIdx.x * 256 + threadIdx.x;
    int r = idx >> 12, c = idx & (NN - 1);
    float g = g_in[idx];
    x[idx] = logf(g / (1.0f - g)) / beta[c];
    unsigned short hi = f2bf(g);
    unsigned short lo = f2bf(g - bf2f(hi));
    size_t off = (((size_t)(c >> 5) * 4 + (r >> 4)) * 64 + ((c & 31) >> 3) * 16 + (r & 15)) * 8 + (c & 7);
    gfh[off] = hi;
    gfl[off] = lo;
}

// ---------------------------------------------------------------------------
// Prologue 3: max_x = 50 / max(beta)
// ---------------------------------------------------------------------------
__global__ __launch_bounds__(256) void maxx_kernel(const float* __restrict__ beta,
                                                   float* __restrict__ out) {
    __shared__ float red[256];
    float m = -1e30f;
    for (int i = threadIdx.x; i < NN; i += 256) m = fmaxf(m, beta[i]);
    red[threadIdx.x] = m;
    __syncthreads();
    for (int s = 128; s > 0; s >>= 1) {
        if (threadIdx.x < s) red[threadIdx.x] = fmaxf(red[threadIdx.x], red[threadIdx.x + s]);
        __syncthreads();
    }
    if (threadIdx.x == 0) out[0] = 50.0f / red[0];
}

// ---------------------------------------------------------------------------
// GEMM kernel v4: split-K, NO in-kernel cross-block sync (v3's fence+atomic
// cost 180 us/step -- the kernel BOUNDARY is the only affordable barrier).
// Grid 256 = 64 strips (64 cols) x 4 K-quarters. g-traffic = 64 blocks'
// worth = 64 MB/step (4x less than v2's 256 strips x 1 MB). kq = bx&3 and
// XCD = bx%8 pin each XCD to ONE g-quarter (256 KB, L2-resident).
// Each block: 16 waves, wave w: nq=w&3 (16-col group), kq4=w>>2 (256-k
// sub-slice); 4-way intra-block kq4 reduction via LDS; float4 P write.
// This is exactly v3's verified GEMM math (absmax 0.00390625) minus sync.
// ---------------------------------------------------------------------------
__global__ __launch_bounds__(1024, 1) void gemm_kernel(
    const unsigned short* __restrict__ gfh,
    const unsigned short* __restrict__ gfl,
    const unsigned short* __restrict__ Wfh,
    const unsigned short* __restrict__ Wfl,
    float* __restrict__ P)                    // [4][64][64][64] fp32 partials
{
    __shared__ float sacc[16][16][65];        // [wave][mq*4+rg][lane], +1 pad

    const int tid  = threadIdx.x;
    const int w    = tid >> 6;
    const int lane = tid & 63;
    const int s64  = blockIdx.x >> 2;         // 64-col strip 0..63
    const int kq   = blockIdx.x & 3;          // K-quarter 0..3 (1024 k)
    const int nq   = w & 3;                   // wave's 16-col group in strip
    const int kq4  = w >> 2;                  // wave's 256-k sub-slice

    f32x4 acc[4] = {};                        // 4 m-subtiles x (16x16) frag

#pragma unroll
    for (int it = 0; it < 8; ++it) {
        const int kc = kq * 32 + kq4 * 8 + it;       // 32-wide K chunk
        const size_t aBase = (size_t)kc * 2048 + lane * 8;          // + mq*512
        const int n16 = s64 * 4 + nq;
        const size_t bOff = (((size_t)n16 * 128 + kc) * 64 + lane) * 8;
        bf16x8 bh = *(const bf16x8*)&Wfh[bOff];
        bf16x8 bl = *(const bf16x8*)&Wfl[bOff];
        bf16x8 ah[4], al[4];
#pragma unroll
        for (int mq = 0; mq < 4; ++mq) {
            ah[mq] = *(const bf16x8*)&gfh[aBase + (size_t)mq * 512];
            al[mq] = *(const bf16x8*)&gfl[aBase + (size_t)mq * 512];
        }
#pragma unroll
        for (int mq = 0; mq < 4; ++mq) {
            acc[mq] = __builtin_amdgcn_mfma_f32_16x16x32_bf16(ah[mq], bh, acc[mq], 0, 0, 0);
            acc[mq] = __builtin_amdgcn_mfma_f32_16x16x32_bf16(al[mq], bh, acc[mq], 0, 0, 0);
            acc[mq] = __builtin_amdgcn_mfma_f32_16x16x32_bf16(ah[mq], bl, acc[mq], 0, 0, 0);
        }
    }

    // Dump wave partials to LDS.
#pragma unroll
    for (int mq = 0; mq < 4; ++mq)
#pragma unroll
        for (int rg = 0; rg < 4; ++rg)
            sacc[w][mq * 4 + rg][lane] = acc[mq][rg];
    __syncthreads();

    // Intra-block 4-way kq4 reduction -> P[kq][s64][64 rows][64 cols].
    // Thread t: row m = t>>4, cols c = (t&15)*4 .. +3 (float4 store).
    {
        const int m  = tid >> 4;
        const int tt = tid & 15;
        const int mq = m >> 4, qq = (m & 15) >> 2, rg = m & 3;
        const int ridx = mq * 4 + rg;
        const int nq_c = tt >> 2;             // (c>>4) for c = tt*4+j
        float4 pv;
#pragma unroll
        for (int j = 0; j < 4; ++j) {
            const int cl = qq * 16 + (tt & 3) * 4 + j;
            (&pv.x)[j] = sacc[nq_c][ridx][cl] + sacc[4 + nq_c][ridx][cl]
                       + sacc[8 + nq_c][ridx][cl] + sacc[12 + nq_c][ridx][cl];
        }
        *(float4*)&P[(((size_t)(kq * 64 + s64) * 64 + m) * 64) + tt * 4] = pv;
    }
}

// ---------------------------------------------------------------------------
// Epilogue kernel v4: grid 256 x 256 thr; block b -> strip s64 = b>>2,
// row-quarter mq4 = b&3 (rows m in [mq4*16, mq4*16+16)). Thread t: local
// row t>>4, cols (t&15)*4..+3. Sums 4 K-quarter partials, applies
// b/alpha/clip/sigmoid, updates x, writes next-step A-fragments (hi/lo),
// plain fp32 g on the last step. Cross-kernel P visibility is guaranteed by
// the dispatch boundary (baseline-proven).
// ---------------------------------------------------------------------------
__global__ __launch_bounds__(256) void epi_kernel(
    const float* __restrict__ P,
    float* __restrict__ x,
    unsigned short* __restrict__ gfh_out,
    unsigned short* __restrict__ gfl_out,
    const float* __restrict__ bvec,
    const float* __restrict__ beta,
    const float* __restrict__ tau,
    const float* __restrict__ dt_ptr,
    const float* __restrict__ maxx_ptr,
    float* __restrict__ gout_f32)             // non-null on last step only
{
    const int tid = threadIdx.x;
    const int s64 = blockIdx.x >> 2;
    const int mq4 = blockIdx.x & 3;
    const int m   = mq4 * 16 + (tid >> 4);    // batch row 0..63
    const int tt  = tid & 15;
    const int c0  = tt * 4;
    const int n0  = s64 * 64 + c0;            // global col, 4-aligned

    const size_t pb = ((size_t)s64 * 64 + m) * 64 + c0;
    float4 p0 = *(const float4*)&P[pb];
    float4 p1 = *(const float4*)&P[(size_t)(1 * 64) * 4096 + pb];
    float4 p2 = *(const float4*)&P[(size_t)(2 * 64) * 4096 + pb];
    float4 p3 = *(const float4*)&P[(size_t)(3 * 64) * 4096 + pb];
    float sum[4] = {p0.x + p1.x + p2.x + p3.x,
                    p0.y + p1.y + p2.y + p3.y,
                    p0.z + p1.z + p2.z + p3.z,
                    p0.w + p1.w + p2.w + p3.w};

    const float dt = *dt_ptr;
    const float mx = *maxx_ptr;
    float4 b0 = *(const float4*)&bvec[n0];
    float4 e0 = *(const float4*)&beta[n0];
    float4 t0 = *(const float4*)&tau[n0];
    float bb[4] = {b0.x, b0.y, b0.z, b0.w};
    float be[4] = {e0.x, e0.y, e0.z, e0.w};
    float tv[4] = {t0.x, t0.y, t0.z, t0.w};

    float* xp = &x[(size_t)m * NN + n0];
    float4 x0 = *(const float4*)xp;
    float xo[4] = {x0.x, x0.y, x0.z, x0.w};

    float gg[4];
    unsigned short vh[4], vl[4];
#pragma unroll
    for (int j = 0; j < 4; ++j) {
        const float al = dt / tv[j];
        float xn = al * (sum[j] + bb[j]) + (1.0f - al) * xo[j];
        xn = fminf(fmaxf(xn, -mx), mx);
        float g = 1.0f / (1.0f + __expf(-be[j] * xn));
        xo[j] = xn;
        gg[j] = g;
        unsigned short hi = f2bf(g);
        vh[j] = hi;
        vl[j] = f2bf(g - bf2f(hi));
    }
    *(float4*)xp = {xo[0], xo[1], xo[2], xo[3]};

    // A-fragment scatter for (m, kg = n0..n0+3); n0%8 in {0,4} -> ushort4.
    size_t off = (((size_t)(n0 >> 5) * 4 + (m >> 4)) * 64 + ((n0 & 31) >> 3) * 16 + (m & 15)) * 8 + (n0 & 7);
    *(ushort4*)&gfh_out[off] = {vh[0], vh[1], vh[2], vh[3]};
    *(ushort4*)&gfl_out[off] = {vl[0], vl[1], vl[2], vl[3]};

    if (gout_f32)
        *(float4*)&gout_f32[(size_t)m * NN + n0] = {gg[0], gg[1], gg[2], gg[3]};
}

// ---------------------------------------------------------------------------
extern "C" void kernel_launch(void* const* d_in, const int* in_sizes, int n_in,
                              void* d_out, int out_size, void* d_ws, size_t ws_size,
                              hipStream_t stream) {
    const float* state_g = (const float*)d_in[0];
    const float* W       = (const float*)d_in[1];
    const float* b       = (const float*)d_in[2];
    const float* beta    = (const float*)d_in[3];
    const float* tau     = (const float*)d_in[4];
    const float* dt      = (const float*)d_in[5];
    float* out = (float*)d_out;

    char* ws = (char*)d_ws;
    const size_t WH = (size_t)KK * NN * 2;    // 32 MB per W-frag array
    const size_t XB = (size_t)MM * NN * 4;    // 1 MB
    const size_t GB = (size_t)MM * NN * 2;    // 512 KB per g-frag array
    const size_t PB = (size_t)4 * 64 * 64 * 64 * 4;   // 4 MB partials
    unsigned short* Wfh = (unsigned short*)ws;
    unsigned short* Wfl = (unsigned short*)(ws + WH);
    float*          x   = (float*)(ws + 2 * WH);
    unsigned short* g0h = (unsigned short*)(ws + 2 * WH + XB);
    unsigned short* g0l = (unsigned short*)(ws + 2 * WH + XB + GB);
    unsigned short* g1h = (unsigned short*)(ws + 2 * WH + XB + 2 * GB);
    unsigned short* g1l = (unsigned short*)(ws + 2 * WH + XB + 3 * GB);
    float*          P   = (float*)(ws + 2 * WH + XB + 4 * GB);
    float*          mxp = (float*)(ws + 2 * WH + XB + 4 * GB + PB);

    symm_kernel<<<dim3(64, 64), 256, 0, stream>>>(W, Wfh, Wfl);
    init_kernel<<<(MM * NN) / 256, 256, 0, stream>>>(state_g, beta, x, g0h, g0l);
    maxx_kernel<<<1, 256, 0, stream>>>(beta, mxp);

    unsigned short *gih = g0h, *gil = g0l, *goh = g1h, *gol = g1l;
    for (int st = 0; st < NSTEP; ++st) {
        float* of = (st == NSTEP - 1) ? out : nullptr;
        gemm_kernel<<<256, 1024, 0, stream>>>(gih, gil, Wfh, Wfl, P);
        epi_kernel<<<256, 256, 0, stream>>>(P, x, goh, gol, b, beta, tau, dt, mxp, of);
        unsigned short* tp;
        tp = gih; gih = goh; goh = tp;
        tp = gil; gil = gol; gol = tp;
    }
}